// Round 9
// baseline (315.962 us; speedup 1.0000x reference)
//
#include <hip/hip_runtime.h>
#include <hip/hip_bf16.h>
#include <math.h>

typedef __hip_bfloat16 bf16;
typedef __attribute__((ext_vector_type(8))) short short8;   // 8 bf16 = 4 VGPRs
typedef __attribute__((ext_vector_type(4))) float f32x4;    // 16x16 MFMA acc
typedef __attribute__((ext_vector_type(16))) float f32x16;  // 32x32 MFMA acc

__device__ __forceinline__ float ldf(const float* p, size_t i) { return p[i]; }
__device__ __forceinline__ float ldf(const bf16*  p, size_t i) { return __bfloat162float(p[i]); }
__device__ __forceinline__ void  stf(float* p, size_t i, float v) { p[i] = v; }
__device__ __forceinline__ void  stf(bf16*  p, size_t i, float v) { p[i] = __float2bfloat16(v); }

__device__ __forceinline__ float ex2(float x) { return __builtin_amdgcn_exp2f(x); }

// async global->LDS, 16 B per lane; dest = wave-uniform base + lane*16 (m97/m104)
__device__ __forceinline__ void gl16(const void* gp, void* lp) {
    __builtin_amdgcn_global_load_lds(
        (const __attribute__((address_space(1))) void*)gp,
        (__attribute__((address_space(3))) void*)lp, 16, 0, 0);
}

// v_permlane32_swap_b32: a' = {a.lo32lanes, b.lo32lanes}, b' = {a.hi, b.hi}
__device__ __forceinline__ void pl32swap(unsigned &a, unsigned &b) {
    asm volatile("v_permlane32_swap_b32 %0, %1" : "+v"(a), "+v"(b));
}

// ---------------------------------------------------------------------------
// fused fp32->bf16 convert: x (4,194,304 elems) then the 6 weight matrices
// (4,194,304 elems) into the contiguous ws region starting at xb.
// ---------------------------------------------------------------------------
__global__ __launch_bounds__(256) void cvt_all(
    const float* __restrict__ x,
    const float* __restrict__ s0, const float* __restrict__ s1,
    const float* __restrict__ s2, const float* __restrict__ s3,
    const float* __restrict__ s4, const float* __restrict__ s5,
    bf16* __restrict__ dst)
{
    int i = blockIdx.x * 256 + threadIdx.x;
    if (i < 4194304) {
        dst[i] = __float2bfloat16(x[i]);
        return;
    }
    int j = i - 4194304;
    const float* s; int off;
    if      (j <  786432) { s = s0; off = 0; }
    else if (j < 1048576) { s = s1; off =  786432; }
    else if (j < 1835008) { s = s2; off = 1048576; }
    else if (j < 2097152) { s = s3; off = 1835008; }
    else if (j < 3145728) { s = s4; off = 2097152; }
    else                  { s = s5; off = 3145728; }
    dst[i] = __float2bfloat16(s[j - off]);
}

// ---------------------------------------------------------------------------
// MFMA GEMM, T14 reg-staged double-buffer (round-6/7 verified structure).
// BN = 128 (4 waves 2x2, 64x64/wave) or BN = 64 (64x32/wave, 3 blk/CU).
// VS > 0 (= S): qkv mode - blocks with col0 >= 1024 hold the V-third; their
// epilogue writes TRANSPOSED to vt[(b*8+h)*64+d][S] and skips C.
// C[M,N] = act(A[M,K] @ W[N,K]^T + bias[N]); EPI: 0=none, 1=exact GELU.
// ---------------------------------------------------------------------------
template <int EPI, int BN, int VS>
__global__ __launch_bounds__(256) void gemm_rs(
    const bf16* __restrict__ A, const bf16* __restrict__ W,
    const float* __restrict__ bias, bf16* __restrict__ C,
    bf16* __restrict__ vt, int M, int N, int K)
{
    constexpr int WNC = BN / 2;     // wave col span
    constexpr int NT  = BN / 32;    // 16-col frags per wave
    constexpr int RB  = BN / 32;    // 32-row staging rounds for B

    __shared__ __align__(16) bf16 Asl[2][128 * 64];
    __shared__ __align__(16) bf16 Bsl[2][BN * 64];

    const int tid  = threadIdx.x;
    const int lane = tid & 63;
    const int wave = tid >> 6;
    const int wm   = wave >> 1, wn = wave & 1;
    const int l15  = lane & 15, quad = lane >> 4;

    // XCD-chunked swizzle (bijective: nwg % 8 == 0 for all launches)
    const int nwg = gridDim.x * gridDim.y;
    const int bid = blockIdx.y * gridDim.x + blockIdx.x;
    const int wid = (bid & 7) * (nwg >> 3) + (bid >> 3);
    const int bx  = wid % gridDim.x, by = wid / gridDim.x;
    const int row0 = by * 128, col0 = bx * BN;

    const int sr = tid >> 3;
    const int gg = tid & 7;

    const bf16* As[4]; const bf16* Ws[RB]; int loA[4], loB[RB];
    #pragma unroll
    for (int j = 0; j < 4; j++) {
        int row = j * 32 + sr;
        int gs  = (gg ^ (row & 7)) * 8;
        As[j]  = &A[(size_t)(row0 + row) * K + gs];
        loA[j] = row * 64 + gg * 8;
    }
    #pragma unroll
    for (int j = 0; j < RB; j++) {
        int row = j * 32 + sr;
        int gs  = (gg ^ (row & 7)) * 8;
        Ws[j]  = &W[(size_t)(col0 + row) * K + gs];
        loB[j] = row * 64 + gg * 8;
    }

    short8 ga[4], gb[RB];
    auto LOADG = [&](int k0) {
        #pragma unroll
        for (int j = 0; j < 4; j++) ga[j] = *(const short8*)(As[j] + k0);
        #pragma unroll
        for (int j = 0; j < RB; j++) gb[j] = *(const short8*)(Ws[j] + k0);
    };
    auto WRITEL = [&](int buf) {
        #pragma unroll
        for (int j = 0; j < 4; j++) *(short8*)&Asl[buf][loA[j]] = ga[j];
        #pragma unroll
        for (int j = 0; j < RB; j++) *(short8*)&Bsl[buf][loB[j]] = gb[j];
    };

    f32x4 acc[4][NT] = {};
    const int nk = K >> 6;

    LOADG(0);
    WRITEL(0);
    __syncthreads();                       // first tile visible

    int cur = 0;
    for (int i = 0; i < nk; i++) {
        if (i + 1 < nk) LOADG((i + 1) << 6);   // in flight over compute

        #pragma unroll
        for (int ks = 0; ks < 64; ks += 32) {
            short8 af[4], bfr[NT];
            const int g0 = (ks >> 3) + quad;
            const int col = (g0 ^ (l15 & 7)) * 8;   // un-swizzle on read
            #pragma unroll
            for (int mt = 0; mt < 4; mt++)
                af[mt] = *(const short8*)&Asl[cur][(wm * 64 + mt * 16 + l15) * 64 + col];
            #pragma unroll
            for (int nt = 0; nt < NT; nt++)
                bfr[nt] = *(const short8*)&Bsl[cur][(wn * WNC + nt * 16 + l15) * 64 + col];
            #pragma unroll
            for (int mt = 0; mt < 4; mt++)
                #pragma unroll
                for (int nt = 0; nt < NT; nt++)
                    acc[mt][nt] = __builtin_amdgcn_mfma_f32_16x16x32_bf16(
                        af[mt], bfr[nt], acc[mt][nt], 0, 0, 0);
        }

        if (i + 1 < nk) WRITEL(cur ^ 1);   // loads already landed (vmcnt)
        __syncthreads();                   // waits only lgkm (ds_writes)
        cur ^= 1;
    }

    if constexpr (VS > 0) {
        if (col0 >= 1024) {                // V-third: transposed store to vt
            constexpr int LS = (VS == 1024) ? 10 : 9;
            #pragma unroll
            for (int mt = 0; mt < 4; mt++) {
                int rowm = row0 + wm * 64 + mt * 16 + quad * 4;
                int b8 = rowm >> LS;
                int s4 = rowm & (VS - 1);
                #pragma unroll
                for (int nt = 0; nt < NT; nt++) {
                    int col = col0 + wn * WNC + nt * 16 + l15;
                    float bv = bias[col];
                    int hd = col - 1024;
                    union { bf16 b4[4]; unsigned long long u; } pk;
                    #pragma unroll
                    for (int r = 0; r < 4; r++)
                        pk.b4[r] = __float2bfloat16(acc[mt][nt][r] + bv);
                    *(unsigned long long*)&vt[
                        ((size_t)(b8 * 8 + (hd >> 6)) * 64 + (hd & 63)) * VS + s4] = pk.u;
                }
            }
            return;
        }
    }

    #pragma unroll
    for (int mt = 0; mt < 4; mt++) {
        int row = row0 + wm * 64 + mt * 16 + quad * 4;
        #pragma unroll
        for (int nt = 0; nt < NT; nt++) {
            int col = col0 + wn * WNC + nt * 16 + l15;
            float bv = bias[col];
            #pragma unroll
            for (int r = 0; r < 4; r++) {
                float v = acc[mt][nt][r] + bv;
                if (EPI == 1) v = 0.5f * v * (1.0f + erff(v * 0.70710678118654752f));
                C[(size_t)(row + r) * N + col] = __float2bfloat16(v);
            }
        }
    }
}

// ---------------------------------------------------------------------------
// MFMA flash attention v6 = v4 (round-7 verified) + KVBLK=128:
//  - 128 k-rows staged per barrier (2x64-tiles) -> HALF the barriers of v4;
//    gl16 with pre-swizzled source into linear [2][128][64] LDS (32 KB,
//    4 blocks/CU at 128 thr)
//  - V fragments for BOTH 64-tiles loaded up-front each iteration (static
//    indices -> registers); second tile's V latency hides under first tile's
//    compute
//  - fixed-bias softmax p = exp2(s*CE - 2); P in registers via cvt_pk +
//    permlane32_swap; s_setprio(1) around MFMA clusters (T5);
//    bijective XCD-chunked swizzle
// ---------------------------------------------------------------------------
template <int LQB>
__global__ __launch_bounds__(128) void flash_attn_mfma(
    const bf16* __restrict__ qkv, const bf16* __restrict__ vt,
    bf16* __restrict__ o)
{
    constexpr int S   = 64 << LQB;
    constexpr int nt2 = 1 << (LQB - 1);    // 128-row iterations

    __shared__ __align__(16) bf16 Kl[2][128 * 64];

    const int tid  = threadIdx.x;
    const int wave = tid >> 6, lane = tid & 63;
    const int l31  = lane & 31, hi = lane >> 5;

    const int r    = blockIdx.x;
    const int w    = (r & 7) * ((1 << LQB) * 8) + (r >> 3);
    const int qblk = w & ((1 << LQB) - 1);
    const int bh   = w >> LQB;
    const int h    = bh & 7, bb = bh >> 3;
    const int q0   = qblk * 64 + wave * 32;

    const bf16* base  = qkv + (size_t)bb * S * 1536 + h * 64;
    const bf16* vbase = vt + (size_t)bh * 64 * S;

    short8 qf[4];
    #pragma unroll
    for (int c = 0; c < 4; c++)
        qf[c] = *(const short8*)&base[(size_t)(q0 + l31) * 1536 + c * 16 + hi * 8];

    const int sr = lane >> 3;
    const int sc = ((lane & 7) ^ sr) * 8;   // swizzled source granule

    auto STGK = [&](int buf, int j) {       // stage k-rows [j*128, j*128+128)
        #pragma unroll
        for (int t = 0; t < 8; t++) {
            int r0 = wave * 64 + t * 8;     // wave-uniform, 8 rows per issue
            gl16(&base[(size_t)((j << 7) + r0 + sr) * 1536 + 512 + sc],
                 &Kl[buf][r0 * 64]);
        }
    };

    f32x16 oacc[2] = {};
    float lrow = 0.f;
    const float CE = 0.18033688f;   // 0.125 * log2(e)

    STGK(0, 0);

    for (int j = 0; j < nt2; j++) {
        const int cur = j & 1;
        __syncthreads();                         // Kl[cur] staged & visible
        if (j + 1 < nt2) STGK(cur ^ 1, j + 1);   // in flight over compute

        // V fragments for both 64-tiles of this 128-row chunk
        short8 vf[2][2][2][2];                   // [t64][sub][kk][dt]
        {
            const bf16* vb = vbase + (j << 7) + hi * 8;
            #pragma unroll
            for (int dt = 0; dt < 2; dt++) {
                const bf16* vd = &vb[(size_t)(dt * 32 + l31) * S];
                #pragma unroll
                for (int t64 = 0; t64 < 2; t64++)
                    #pragma unroll
                    for (int sub = 0; sub < 2; sub++)
                        #pragma unroll
                        for (int kk = 0; kk < 2; kk++)
                            vf[t64][sub][kk][dt] =
                                *(const short8*)&vd[t64 * 64 + sub * 32 + kk * 16];
            }
        }

        #pragma unroll
        for (int t64 = 0; t64 < 2; t64++) {
            const bf16* Kc = &Kl[cur][t64 * 64 * 64];
            #pragma unroll
            for (int sub = 0; sub < 2; sub++) {
                f32x16 st = {};
                __builtin_amdgcn_s_setprio(1);
                #pragma unroll
                for (int c = 0; c < 4; c++) {
                    const int row  = sub * 32 + l31;
                    const int slot = (c * 2 + hi) ^ (row & 7);
                    short8 af = *(const short8*)&Kc[row * 64 + slot * 8];
                    st = __builtin_amdgcn_mfma_f32_32x32x16_bf16(af, qf[c], st, 0, 0, 0);
                }
                __builtin_amdgcn_s_setprio(0);

                float p[16]; float ps = 0.f;
                #pragma unroll
                for (int r2 = 0; r2 < 16; r2++) {
                    p[r2] = ex2(st[r2] * CE - 2.0f);
                    ps += p[r2];
                }
                lrow += ps;

                unsigned wk[8];
                #pragma unroll
                for (int jj = 0; jj < 8; jj++)
                    asm("v_cvt_pk_bf16_f32 %0, %1, %2"
                        : "=v"(wk[jj]) : "v"(p[2*jj]), "v"(p[2*jj+1]));

                __builtin_amdgcn_s_setprio(1);
                #pragma unroll
                for (int kk = 0; kk < 2; kk++) {
                    pl32swap(wk[kk*4+0], wk[kk*4+2]);
                    pl32swap(wk[kk*4+1], wk[kk*4+3]);
                    union { unsigned u[4]; short8 s; } pa;
                    pa.u[0] = wk[kk*4+0]; pa.u[1] = wk[kk*4+1];
                    pa.u[2] = wk[kk*4+2]; pa.u[3] = wk[kk*4+3];
                    #pragma unroll
                    for (int dt = 0; dt < 2; dt++)
                        oacc[dt] = __builtin_amdgcn_mfma_f32_32x32x16_bf16(
                            pa.s, vf[t64][sub][kk][dt], oacc[dt], 0, 0, 0);
                }
                __builtin_amdgcn_s_setprio(0);
            }
        }
    }

    lrow += __shfl_xor(lrow, 32);
    float inv = 1.0f / lrow;
    #pragma unroll
    for (int r2 = 0; r2 < 16; r2++) {
        int qr = (r2 & 3) + 8 * (r2 >> 2) + 4 * hi;
        float iv = __shfl(inv, qr);
        size_t rb = ((size_t)bb * S + q0 + qr) * 512 + h * 64;
        o[rb + l31]      = __float2bfloat16(oacc[0][r2] * iv);
        o[rb + 32 + l31] = __float2bfloat16(oacc[1][r2] * iv);
    }
}

// ---------------------------------------------------------------------------
// out = LN(a + b) * g + beta over D=512. One block (256 thr) per row.
// ---------------------------------------------------------------------------
template <typename AT, typename OT, bool INTERP>
__global__ __launch_bounds__(256) void ln_kernel(
    const AT* __restrict__ a, const bf16* __restrict__ bsrc,
    const float* __restrict__ g, const float* __restrict__ beta,
    OT* __restrict__ out)
{
    const int row = blockIdx.x;
    const int t = threadIdx.x;
    const size_t base = (size_t)row * 512;

    float a0 = ldf(a, base + t), a1 = ldf(a, base + t + 256);
    float b0, b1;
    if (INTERP) {
        int s = row & 1023, bb = row >> 10;
        float src = fminf(fmaxf((s + 0.5f) * 0.5f - 0.5f, 0.f), 511.f);
        int i0 = (int)src;
        int i1 = min(i0 + 1, 511);
        float w = src - (float)i0;
        size_t r0 = ((size_t)bb * 512 + i0) * 512;
        size_t r1 = ((size_t)bb * 512 + i1) * 512;
        b0 = __bfloat162float(bsrc[r0 + t]) * (1.f - w) + __bfloat162float(bsrc[r1 + t]) * w;
        b1 = __bfloat162float(bsrc[r0 + t + 256]) * (1.f - w) + __bfloat162float(bsrc[r1 + t + 256]) * w;
    } else {
        b0 = __bfloat162float(bsrc[base + t]);
        b1 = __bfloat162float(bsrc[base + t + 256]);
    }
    float v0 = a0 + b0, v1 = a1 + b1;

    __shared__ float red[4];
    const int lane = t & 63, wid = t >> 6;

    float sm = v0 + v1;
    #pragma unroll
    for (int off = 32; off > 0; off >>= 1) sm += __shfl_xor(sm, off);
    if (lane == 0) red[wid] = sm;
    __syncthreads();
    sm = red[0] + red[1] + red[2] + red[3];
    const float mean = sm * (1.0f / 512.0f);

    float d0 = v0 - mean, d1 = v1 - mean;
    float vv = d0 * d0 + d1 * d1;
    __syncthreads();
    #pragma unroll
    for (int off = 32; off > 0; off >>= 1) vv += __shfl_xor(vv, off);
    if (lane == 0) red[wid] = vv;
    __syncthreads();
    vv = red[0] + red[1] + red[2] + red[3];
    const float rstd = rsqrtf(vv * (1.0f / 512.0f) + 1e-5f);

    stf(out, base + t,       d0 * rstd * g[t]       + beta[t]);
    stf(out, base + t + 256, d1 * rstd * g[t + 256] + beta[t + 256]);
}

// ---------------------------------------------------------------------------
// Fused ln1 + avg_pool: one block per ROW-PAIR (2s, 2s+1). Computes both
// LN rows of x1 and the pooled row = 0.5*(x1[2s]+x1[2s+1]).
// ---------------------------------------------------------------------------
__global__ __launch_bounds__(256) void ln_pool_kernel(
    const float* __restrict__ a, const bf16* __restrict__ bsrc,
    const float* __restrict__ g, const float* __restrict__ beta,
    bf16* __restrict__ x1, bf16* __restrict__ pooled)
{
    const int pr = blockIdx.x;              // pooled row 0..4095
    const int t = threadIdx.x;
    const size_t base0 = (size_t)(2 * pr) * 512;
    const size_t base1 = base0 + 512;

    float u0 = a[base0 + t]       + __bfloat162float(bsrc[base0 + t]);
    float u1 = a[base0 + t + 256] + __bfloat162float(bsrc[base0 + t + 256]);
    float w0 = a[base1 + t]       + __bfloat162float(bsrc[base1 + t]);
    float w1 = a[base1 + t + 256] + __bfloat162float(bsrc[base1 + t + 256]);

    __shared__ float red[2][4];
    const int lane = t & 63, wid = t >> 6;

    float s0 = u0 + u1, s1 = w0 + w1;
    #pragma unroll
    for (int off = 32; off > 0; off >>= 1) {
        s0 += __shfl_xor(s0, off);
        s1 += __shfl_xor(s1, off);
    }
    if (lane == 0) { red[0][wid] = s0; red[1][wid] = s1; }
    __syncthreads();
    const float m0 = (red[0][0] + red[0][1] + red[0][2] + red[0][3]) * (1.0f / 512.0f);
    const float m1 = (red[1][0] + red[1][1] + red[1][2] + red[1][3]) * (1.0f / 512.0f);

    float du0 = u0 - m0, du1 = u1 - m0, dw0 = w0 - m1, dw1 = w1 - m1;
    float v0 = du0 * du0 + du1 * du1, v1 = dw0 * dw0 + dw1 * dw1;
    __syncthreads();
    #pragma unroll
    for (int off = 32; off > 0; off >>= 1) {
        v0 += __shfl_xor(v0, off);
        v1 += __shfl_xor(v1, off);
    }
    if (lane == 0) { red[0][wid] = v0; red[1][wid] = v1; }
    __syncthreads();
    const float r0 = rsqrtf((red[0][0] + red[0][1] + red[0][2] + red[0][3]) * (1.0f / 512.0f) + 1e-5f);
    const float r1 = rsqrtf((red[1][0] + red[1][1] + red[1][2] + red[1][3]) * (1.0f / 512.0f) + 1e-5f);

    float g0 = g[t], g1v = g[t + 256], be0 = beta[t], be1 = beta[t + 256];
    float y00 = du0 * r0 * g0  + be0;
    float y01 = du1 * r0 * g1v + be1;
    float y10 = dw0 * r1 * g0  + be0;
    float y11 = dw1 * r1 * g1v + be1;

    x1[base0 + t]       = __float2bfloat16(y00);
    x1[base0 + t + 256] = __float2bfloat16(y01);
    x1[base1 + t]       = __float2bfloat16(y10);
    x1[base1 + t + 256] = __float2bfloat16(y11);

    const size_t pb = (size_t)pr * 512;
    pooled[pb + t]       = __float2bfloat16(0.5f * (y00 + y10));
    pooled[pb + t + 256] = __float2bfloat16(0.5f * (y01 + y11));
}

// ---------------------------------------------------------------------------
// launch
// ---------------------------------------------------------------------------
extern "C" void kernel_launch(void* const* d_in, const int* in_sizes, int n_in,
                              void* d_out, int out_size, void* d_ws, size_t ws_size,
                              hipStream_t stream)
{
    const float* x      = (const float*)d_in[0];
    const float* w_in1  = (const float*)d_in[1];
    const float* b_in1  = (const float*)d_in[2];
    const float* w_out1 = (const float*)d_in[3];
    const float* b_out1 = (const float*)d_in[4];
    const float* w_in2  = (const float*)d_in[5];
    const float* b_in2  = (const float*)d_in[6];
    const float* w_out2 = (const float*)d_in[7];
    const float* b_out2 = (const float*)d_in[8];
    const float* g1     = (const float*)d_in[9];
    const float* be1    = (const float*)d_in[10];
    const float* g2     = (const float*)d_in[11];
    const float* be2    = (const float*)d_in[12];
    const float* g3     = (const float*)d_in[13];
    const float* be3    = (const float*)d_in[14];
    const float* w_ff1  = (const float*)d_in[15];
    const float* b_ff1  = (const float*)d_in[16];
    const float* w_ff2  = (const float*)d_in[17];
    const float* b_ff2  = (const float*)d_in[18];

    // workspace: bf16 elements; peak 50,331,648 elems = 100.66 MB (proven size)
    bf16* ws     = (bf16*)d_ws;
    bf16* xb     = ws + 0;            // [8,1024, 512]
    bf16* wq1    = ws + 4194304;      // [1536,512]   -- weights contiguous:
    bf16* wo1    = ws + 4980736;      // [512,512]
    bf16* wq2    = ws + 5242880;      // [1536,512]
    bf16* wo2    = ws + 6029312;      // [512,512]
    bf16* wf1    = ws + 6291456;      // [2048,512]
    bf16* wf2    = ws + 7340032;      // [512,2048]
    bf16* qkv1   = ws + 8388608;      // [8,1024,1536]
    bf16* o1     = ws + 20971520;     // [8,1024, 512]
    bf16* a1     = ws + 25165824;     // [8,1024, 512]
    bf16* x1     = ws + 29360128;     // [8,1024, 512]
    bf16* pooled = ws + 33554432;     // [8, 512, 512]
    bf16* qkv2   = ws + 35651584;     // [8, 512,1536]
    bf16* o2     = ws + 41943040;     // [8, 512, 512]
    bf16* a2     = ws + 44040192;     // [8, 512, 512]
    bf16* x2     = ws + 46137344;     // [8,1024, 512]
    bf16* h      = ws + 8388608;      // [8,1024,2048] (qkv1/o1 dead)
    bf16* ff     = ws + 25165824;     // [8,1024, 512] (a1 dead)
    bf16* vt     = ws + 46137344;     // [4096,1024] (x2 slot; dead before ln2 writes x2)

    dim3 blk(256);
    dim3 fblk(128);

    cvt_all<<<32768, blk, 0, stream>>>(x, w_in1, w_out1, w_in2, w_out2, w_ff1, w_ff2, xb);

    gemm_rs<0,128,1024><<<dim3(12, 64), blk, 0, stream>>>(xb, wq1, b_in1, qkv1, vt, 8192, 1536, 512);
    flash_attn_mfma<4><<<dim3(1024), fblk, 0, stream>>>(qkv1, vt, o1);
    gemm_rs<0,64,0><<<dim3(8, 64), blk, 0, stream>>>(o1, wo1, b_out1, a1, nullptr, 8192, 512, 512);
    ln_pool_kernel<<<4096, blk, 0, stream>>>(x, a1, g1, be1, x1, pooled);
    gemm_rs<0,64,512><<<dim3(24, 32), blk, 0, stream>>>(pooled, wq2, b_in2, qkv2, vt, 4096, 1536, 512);
    flash_attn_mfma<3><<<dim3(512), fblk, 0, stream>>>(qkv2, vt, o2);
    gemm_rs<0,64,0><<<dim3(8, 32), blk, 0, stream>>>(o2, wo2, b_out2, a2, nullptr, 4096, 512, 512);
    ln_kernel<bf16, bf16, true><<<8192, blk, 0, stream>>>(x1, a2, g2, be2, x2);
    gemm_rs<1,128,0><<<dim3(16, 64), blk, 0, stream>>>(x2, wf1, b_ff1, h, nullptr, 8192, 2048, 512);
    gemm_rs<0,64,0><<<dim3(8, 64), blk, 0, stream>>>(h, wf2, b_ff2, ff, nullptr, 8192, 512, 2048);
    ln_kernel<bf16, float, false><<<8192, blk, 0, stream>>>(x2, ff, g3, be3, (float*)d_out);
}

// Round 10
// 302.859 us; speedup vs baseline: 1.0433x; 1.0433x over previous
//
#include <hip/hip_runtime.h>
#include <hip/hip_bf16.h>
#include <math.h>

typedef __hip_bfloat16 bf16;
typedef __attribute__((ext_vector_type(8))) short short8;   // 8 bf16 = 4 VGPRs
typedef __attribute__((ext_vector_type(4))) float f32x4;    // 16x16 MFMA acc
typedef __attribute__((ext_vector_type(16))) float f32x16;  // 32x32 MFMA acc

__device__ __forceinline__ float ldf(const float* p, size_t i) { return p[i]; }
__device__ __forceinline__ float ldf(const bf16*  p, size_t i) { return __bfloat162float(p[i]); }
__device__ __forceinline__ void  stf(float* p, size_t i, float v) { p[i] = v; }
__device__ __forceinline__ void  stf(bf16*  p, size_t i, float v) { p[i] = __float2bfloat16(v); }

__device__ __forceinline__ float ex2(float x) { return __builtin_amdgcn_exp2f(x); }

// async global->LDS, 16 B per lane; dest = wave-uniform base + lane*16 (m97/m104)
__device__ __forceinline__ void gl16(const void* gp, void* lp) {
    __builtin_amdgcn_global_load_lds(
        (const __attribute__((address_space(1))) void*)gp,
        (__attribute__((address_space(3))) void*)lp, 16, 0, 0);
}

// v_permlane32_swap_b32: a' = {a.lo32lanes, b.lo32lanes}, b' = {a.hi, b.hi}
__device__ __forceinline__ void pl32swap(unsigned &a, unsigned &b) {
    asm volatile("v_permlane32_swap_b32 %0, %1" : "+v"(a), "+v"(b));
}

// ---------------------------------------------------------------------------
// fused fp32->bf16 convert: x (4,194,304 elems) then the 6 weight matrices
// (4,194,304 elems) into the contiguous ws region starting at xb.
// ---------------------------------------------------------------------------
__global__ __launch_bounds__(256) void cvt_all(
    const float* __restrict__ x,
    const float* __restrict__ s0, const float* __restrict__ s1,
    const float* __restrict__ s2, const float* __restrict__ s3,
    const float* __restrict__ s4, const float* __restrict__ s5,
    bf16* __restrict__ dst)
{
    int i = blockIdx.x * 256 + threadIdx.x;
    if (i < 4194304) {
        dst[i] = __float2bfloat16(x[i]);
        return;
    }
    int j = i - 4194304;
    const float* s; int off;
    if      (j <  786432) { s = s0; off = 0; }
    else if (j < 1048576) { s = s1; off =  786432; }
    else if (j < 1835008) { s = s2; off = 1048576; }
    else if (j < 2097152) { s = s3; off = 1835008; }
    else if (j < 3145728) { s = s4; off = 2097152; }
    else                  { s = s5; off = 3145728; }
    dst[i] = __float2bfloat16(s[j - off]);
}

// ---------------------------------------------------------------------------
// MFMA GEMM, T14 reg-staged double-buffer (round-6/7 verified structure).
// BN = 128 (4 waves 2x2, 64x64/wave) or BN = 64 (64x32/wave, 3 blk/CU).
// VS > 0 (= S): qkv mode - blocks with col0 >= 1024 hold the V-third; their
// epilogue writes TRANSPOSED to vt[(b*8+h)*64+d][S] and skips C.
// C[M,N] = act(A[M,K] @ W[N,K]^T + bias[N]); EPI: 0=none, 1=exact GELU.
// ---------------------------------------------------------------------------
template <int EPI, int BN, int VS>
__global__ __launch_bounds__(256) void gemm_rs(
    const bf16* __restrict__ A, const bf16* __restrict__ W,
    const float* __restrict__ bias, bf16* __restrict__ C,
    bf16* __restrict__ vt, int M, int N, int K)
{
    constexpr int WNC = BN / 2;     // wave col span
    constexpr int NT  = BN / 32;    // 16-col frags per wave
    constexpr int RB  = BN / 32;    // 32-row staging rounds for B

    __shared__ __align__(16) bf16 Asl[2][128 * 64];
    __shared__ __align__(16) bf16 Bsl[2][BN * 64];

    const int tid  = threadIdx.x;
    const int lane = tid & 63;
    const int wave = tid >> 6;
    const int wm   = wave >> 1, wn = wave & 1;
    const int l15  = lane & 15, quad = lane >> 4;

    // XCD-chunked swizzle (bijective: nwg % 8 == 0 for all launches)
    const int nwg = gridDim.x * gridDim.y;
    const int bid = blockIdx.y * gridDim.x + blockIdx.x;
    const int wid = (bid & 7) * (nwg >> 3) + (bid >> 3);
    const int bx  = wid % gridDim.x, by = wid / gridDim.x;
    const int row0 = by * 128, col0 = bx * BN;

    const int sr = tid >> 3;
    const int gg = tid & 7;

    const bf16* As[4]; const bf16* Ws[RB]; int loA[4], loB[RB];
    #pragma unroll
    for (int j = 0; j < 4; j++) {
        int row = j * 32 + sr;
        int gs  = (gg ^ (row & 7)) * 8;
        As[j]  = &A[(size_t)(row0 + row) * K + gs];
        loA[j] = row * 64 + gg * 8;
    }
    #pragma unroll
    for (int j = 0; j < RB; j++) {
        int row = j * 32 + sr;
        int gs  = (gg ^ (row & 7)) * 8;
        Ws[j]  = &W[(size_t)(col0 + row) * K + gs];
        loB[j] = row * 64 + gg * 8;
    }

    short8 ga[4], gb[RB];
    auto LOADG = [&](int k0) {
        #pragma unroll
        for (int j = 0; j < 4; j++) ga[j] = *(const short8*)(As[j] + k0);
        #pragma unroll
        for (int j = 0; j < RB; j++) gb[j] = *(const short8*)(Ws[j] + k0);
    };
    auto WRITEL = [&](int buf) {
        #pragma unroll
        for (int j = 0; j < 4; j++) *(short8*)&Asl[buf][loA[j]] = ga[j];
        #pragma unroll
        for (int j = 0; j < RB; j++) *(short8*)&Bsl[buf][loB[j]] = gb[j];
    };

    f32x4 acc[4][NT] = {};
    const int nk = K >> 6;

    LOADG(0);
    WRITEL(0);
    __syncthreads();                       // first tile visible

    int cur = 0;
    for (int i = 0; i < nk; i++) {
        if (i + 1 < nk) LOADG((i + 1) << 6);   // in flight over compute

        #pragma unroll
        for (int ks = 0; ks < 64; ks += 32) {
            short8 af[4], bfr[NT];
            const int g0 = (ks >> 3) + quad;
            const int col = (g0 ^ (l15 & 7)) * 8;   // un-swizzle on read
            #pragma unroll
            for (int mt = 0; mt < 4; mt++)
                af[mt] = *(const short8*)&Asl[cur][(wm * 64 + mt * 16 + l15) * 64 + col];
            #pragma unroll
            for (int nt = 0; nt < NT; nt++)
                bfr[nt] = *(const short8*)&Bsl[cur][(wn * WNC + nt * 16 + l15) * 64 + col];
            #pragma unroll
            for (int mt = 0; mt < 4; mt++)
                #pragma unroll
                for (int nt = 0; nt < NT; nt++)
                    acc[mt][nt] = __builtin_amdgcn_mfma_f32_16x16x32_bf16(
                        af[mt], bfr[nt], acc[mt][nt], 0, 0, 0);
        }

        if (i + 1 < nk) WRITEL(cur ^ 1);   // loads already landed (vmcnt)
        __syncthreads();                   // waits only lgkm (ds_writes)
        cur ^= 1;
    }

    if constexpr (VS > 0) {
        if (col0 >= 1024) {                // V-third: transposed store to vt
            constexpr int LS = (VS == 1024) ? 10 : 9;
            #pragma unroll
            for (int mt = 0; mt < 4; mt++) {
                int rowm = row0 + wm * 64 + mt * 16 + quad * 4;
                int b8 = rowm >> LS;
                int s4 = rowm & (VS - 1);
                #pragma unroll
                for (int nt = 0; nt < NT; nt++) {
                    int col = col0 + wn * WNC + nt * 16 + l15;
                    float bv = bias[col];
                    int hd = col - 1024;
                    union { bf16 b4[4]; unsigned long long u; } pk;
                    #pragma unroll
                    for (int r = 0; r < 4; r++)
                        pk.b4[r] = __float2bfloat16(acc[mt][nt][r] + bv);
                    *(unsigned long long*)&vt[
                        ((size_t)(b8 * 8 + (hd >> 6)) * 64 + (hd & 63)) * VS + s4] = pk.u;
                }
            }
            return;
        }
    }

    #pragma unroll
    for (int mt = 0; mt < 4; mt++) {
        int row = row0 + wm * 64 + mt * 16 + quad * 4;
        #pragma unroll
        for (int nt = 0; nt < NT; nt++) {
            int col = col0 + wn * WNC + nt * 16 + l15;
            float bv = bias[col];
            #pragma unroll
            for (int r = 0; r < 4; r++) {
                float v = acc[mt][nt][r] + bv;
                if (EPI == 1) v = 0.5f * v * (1.0f + erff(v * 0.70710678118654752f));
                C[(size_t)(row + r) * N + col] = __float2bfloat16(v);
            }
        }
    }
}

// ---------------------------------------------------------------------------
// MFMA flash attention v7 = v4 (round-7 verified, 42.6us) + V staged to LDS:
//  - K staged via gl16 with pre-swizzled SOURCE into linear [2][64][64] LDS
//    (unchanged from v4); one barrier per k-tile
//  - NEW: V ALSO staged via gl16 into a second swizzled LDS buffer. vt is
//    d-major so rows are s-contiguous -> coalesced DMA (64 line-requests
//    per tile vs ~256 scattered L1 probes for the v4 global vf loads, which
//    is the theorized hidden TA bottleneck). PV B-frags become 2-way-free
//    ds_read_b128 with the identical swizzle algebra as the K path.
//  - fixed-bias softmax p = exp2(s*CE - 2); P in registers via cvt_pk +
//    permlane32_swap (T12); bijective XCD-chunked swizzle
// ---------------------------------------------------------------------------
template <int LQB>
__global__ __launch_bounds__(128) void flash_attn_mfma(
    const bf16* __restrict__ qkv, const bf16* __restrict__ vt,
    bf16* __restrict__ o)
{
    constexpr int S  = 64 << LQB;
    constexpr int nt = 1 << LQB;

    __shared__ __align__(16) bf16 Kl[2][64 * 64];
    __shared__ __align__(16) bf16 Vl[2][64 * 64];

    const int tid  = threadIdx.x;
    const int wave = tid >> 6, lane = tid & 63;
    const int l31  = lane & 31, hi = lane >> 5;

    const int r    = blockIdx.x;
    const int w    = (r & 7) * ((1 << LQB) * 8) + (r >> 3);
    const int qblk = w & ((1 << LQB) - 1);
    const int bh   = w >> LQB;
    const int h    = bh & 7, bb = bh >> 3;
    const int q0   = qblk * 64 + wave * 32;

    const bf16* base  = qkv + (size_t)bb * S * 1536 + h * 64;
    const bf16* vbase = vt + (size_t)bh * 64 * S;

    // Q fragments: lane(q=l31, hi) holds Q[q][c*16 + hi*8 + e]  (B-frag)
    short8 qf[4];
    #pragma unroll
    for (int c = 0; c < 4; c++)
        qf[c] = *(const short8*)&base[(size_t)(q0 + l31) * 1536 + c * 16 + hi * 8];

    const int sr = lane >> 3;
    const int sc = ((lane & 7) ^ sr) * 8;   // swizzled source granule

    auto STGKV = [&](int buf, int k0) {
        #pragma unroll
        for (int t = 0; t < 4; t++) {
            int r0 = wave * 32 + t * 8;     // k-rows, wave-uniform
            gl16(&base[(size_t)(k0 + r0 + sr) * 1536 + 512 + sc], &Kl[buf][r0 * 64]);
        }
        #pragma unroll
        for (int t = 0; t < 4; t++) {
            int r0 = wave * 32 + t * 8;     // d-rows of V^T, wave-uniform
            gl16(&vbase[(size_t)(r0 + sr) * S + k0 + sc], &Vl[buf][r0 * 64]);
        }
    };

    f32x16 oacc[2] = {};
    float lrow = 0.f;
    const float CE = 0.18033688f;   // 0.125 * log2(e)

    STGKV(0, 0);

    for (int it = 0; it < nt; it++) {
        const int cur = it & 1;
        __syncthreads();                         // Kl/Vl[cur] staged & visible
        if (it + 1 < nt) STGKV(cur ^ 1, (it + 1) << 6);   // in flight over compute

        const bf16* Kc = &Kl[cur][0];
        const bf16* Vc = &Vl[cur][0];
        #pragma unroll
        for (int sub = 0; sub < 2; sub++) {
            // S^T = K @ Q^T (32k x 32q); lane(l31=q): k=(r2&3)+8*(r2>>2)+4*hi
            f32x16 st = {};
            #pragma unroll
            for (int c = 0; c < 4; c++) {
                const int row  = sub * 32 + l31;
                const int slot = (c * 2 + hi) ^ (row & 7);
                short8 af = *(const short8*)&Kc[row * 64 + slot * 8];
                st = __builtin_amdgcn_mfma_f32_32x32x16_bf16(af, qf[c], st, 0, 0, 0);
            }

            // fixed-bias exp2; per-lane partial row sum (combined at end)
            float p[16]; float ps = 0.f;
            #pragma unroll
            for (int r2 = 0; r2 < 16; r2++) {
                p[r2] = ex2(st[r2] * CE - 2.0f);
                ps += p[r2];
            }
            lrow += ps;

            unsigned wk[8];
            #pragma unroll
            for (int jj = 0; jj < 8; jj++)
                asm("v_cvt_pk_bf16_f32 %0, %1, %2"
                    : "=v"(wk[jj]) : "v"(p[2*jj]), "v"(p[2*jj+1]));

            #pragma unroll
            for (int kk = 0; kk < 2; kk++) {
                pl32swap(wk[kk*4+0], wk[kk*4+2]);
                pl32swap(wk[kk*4+1], wk[kk*4+3]);
                union { unsigned u[4]; short8 s; } pa;
                pa.u[0] = wk[kk*4+0]; pa.u[1] = wk[kk*4+1];
                pa.u[2] = wk[kk*4+2]; pa.u[3] = wk[kk*4+3];
                #pragma unroll
                for (int dt = 0; dt < 2; dt++) {
                    const int row  = dt * 32 + l31;               // d-row
                    const int slot = (sub * 4 + kk * 2 + hi) ^ (row & 7);
                    short8 vf = *(const short8*)&Vc[row * 64 + slot * 8];
                    oacc[dt] = __builtin_amdgcn_mfma_f32_32x32x16_bf16(
                        pa.s, vf, oacc[dt], 0, 0, 0);
                }
            }
        }
    }

    // combine the two k-halves of each q-row, normalize, store
    lrow += __shfl_xor(lrow, 32);
    float inv = 1.0f / lrow;
    #pragma unroll
    for (int r2 = 0; r2 < 16; r2++) {
        int qr = (r2 & 3) + 8 * (r2 >> 2) + 4 * hi;
        float iv = __shfl(inv, qr);
        size_t rb = ((size_t)bb * S + q0 + qr) * 512 + h * 64;
        o[rb + l31]      = __float2bfloat16(oacc[0][r2] * iv);
        o[rb + 32 + l31] = __float2bfloat16(oacc[1][r2] * iv);
    }
}

// ---------------------------------------------------------------------------
// out = LN(a + b) * g + beta over D=512. One block (256 thr) per row.
// ---------------------------------------------------------------------------
template <typename AT, typename OT, bool INTERP>
__global__ __launch_bounds__(256) void ln_kernel(
    const AT* __restrict__ a, const bf16* __restrict__ bsrc,
    const float* __restrict__ g, const float* __restrict__ beta,
    OT* __restrict__ out)
{
    const int row = blockIdx.x;
    const int t = threadIdx.x;
    const size_t base = (size_t)row * 512;

    float a0 = ldf(a, base + t), a1 = ldf(a, base + t + 256);
    float b0, b1;
    if (INTERP) {
        int s = row & 1023, bb = row >> 10;
        float src = fminf(fmaxf((s + 0.5f) * 0.5f - 0.5f, 0.f), 511.f);
        int i0 = (int)src;
        int i1 = min(i0 + 1, 511);
        float w = src - (float)i0;
        size_t r0 = ((size_t)bb * 512 + i0) * 512;
        size_t r1 = ((size_t)bb * 512 + i1) * 512;
        b0 = __bfloat162float(bsrc[r0 + t]) * (1.f - w) + __bfloat162float(bsrc[r1 + t]) * w;
        b1 = __bfloat162float(bsrc[r0 + t + 256]) * (1.f - w) + __bfloat162float(bsrc[r1 + t + 256]) * w;
    } else {
        b0 = __bfloat162float(bsrc[base + t]);
        b1 = __bfloat162float(bsrc[base + t + 256]);
    }
    float v0 = a0 + b0, v1 = a1 + b1;

    __shared__ float red[4];
    const int lane = t & 63, wid = t >> 6;

    float sm = v0 + v1;
    #pragma unroll
    for (int off = 32; off > 0; off >>= 1) sm += __shfl_xor(sm, off);
    if (lane == 0) red[wid] = sm;
    __syncthreads();
    sm = red[0] + red[1] + red[2] + red[3];
    const float mean = sm * (1.0f / 512.0f);

    float d0 = v0 - mean, d1 = v1 - mean;
    float vv = d0 * d0 + d1 * d1;
    __syncthreads();
    #pragma unroll
    for (int off = 32; off > 0; off >>= 1) vv += __shfl_xor(vv, off);
    if (lane == 0) red[wid] = vv;
    __syncthreads();
    vv = red[0] + red[1] + red[2] + red[3];
    const float rstd = rsqrtf(vv * (1.0f / 512.0f) + 1e-5f);

    stf(out, base + t,       d0 * rstd * g[t]       + beta[t]);
    stf(out, base + t + 256, d1 * rstd * g[t + 256] + beta[t + 256]);
}

// ---------------------------------------------------------------------------
// Fused ln1 + avg_pool: one block per ROW-PAIR (2s, 2s+1). Computes both
// LN rows of x1 and the pooled row = 0.5*(x1[2s]+x1[2s+1]).
// ---------------------------------------------------------------------------
__global__ __launch_bounds__(256) void ln_pool_kernel(
    const float* __restrict__ a, const bf16* __restrict__ bsrc,
    const float* __restrict__ g, const float* __restrict__ beta,
    bf16* __restrict__ x1, bf16* __restrict__ pooled)
{
    const int pr = blockIdx.x;              // pooled row 0..4095
    const int t = threadIdx.x;
    const size_t base0 = (size_t)(2 * pr) * 512;
    const size_t base1 = base0 + 512;

    float u0 = a[base0 + t]       + __bfloat162float(bsrc[base0 + t]);
    float u1 = a[base0 + t + 256] + __bfloat162float(bsrc[base0 + t + 256]);
    float w0 = a[base1 + t]       + __bfloat162float(bsrc[base1 + t]);
    float w1 = a[base1 + t + 256] + __bfloat162float(bsrc[base1 + t + 256]);

    __shared__ float red[2][4];
    const int lane = t & 63, wid = t >> 6;

    float s0 = u0 + u1, s1 = w0 + w1;
    #pragma unroll
    for (int off = 32; off > 0; off >>= 1) {
        s0 += __shfl_xor(s0, off);
        s1 += __shfl_xor(s1, off);
    }
    if (lane == 0) { red[0][wid] = s0; red[1][wid] = s1; }
    __syncthreads();
    const float m0 = (red[0][0] + red[0][1] + red[0][2] + red[0][3]) * (1.0f / 512.0f);
    const float m1 = (red[1][0] + red[1][1] + red[1][2] + red[1][3]) * (1.0f / 512.0f);

    float du0 = u0 - m0, du1 = u1 - m0, dw0 = w0 - m1, dw1 = w1 - m1;
    float v0 = du0 * du0 + du1 * du1, v1 = dw0 * dw0 + dw1 * dw1;
    __syncthreads();
    #pragma unroll
    for (int off = 32; off > 0; off >>= 1) {
        v0 += __shfl_xor(v0, off);
        v1 += __shfl_xor(v1, off);
    }
    if (lane == 0) { red[0][wid] = v0; red[1][wid] = v1; }
    __syncthreads();
    const float r0 = rsqrtf((red[0][0] + red[0][1] + red[0][2] + red[0][3]) * (1.0f / 512.0f) + 1e-5f);
    const float r1 = rsqrtf((red[1][0] + red[1][1] + red[1][2] + red[1][3]) * (1.0f / 512.0f) + 1e-5f);

    float g0 = g[t], g1v = g[t + 256], be0 = beta[t], be1 = beta[t + 256];
    float y00 = du0 * r0 * g0  + be0;
    float y01 = du1 * r0 * g1v + be1;
    float y10 = dw0 * r1 * g0  + be0;
    float y11 = dw1 * r1 * g1v + be1;

    x1[base0 + t]       = __float2bfloat16(y00);
    x1[base0 + t + 256] = __float2bfloat16(y01);
    x1[base1 + t]       = __float2bfloat16(y10);
    x1[base1 + t + 256] = __float2bfloat16(y11);

    const size_t pb = (size_t)pr * 512;
    pooled[pb + t]       = __float2bfloat16(0.5f * (y00 + y10));
    pooled[pb + t + 256] = __float2bfloat16(0.5f * (y01 + y11));
}

// ---------------------------------------------------------------------------
// launch
// ---------------------------------------------------------------------------
extern "C" void kernel_launch(void* const* d_in, const int* in_sizes, int n_in,
                              void* d_out, int out_size, void* d_ws, size_t ws_size,
                              hipStream_t stream)
{
    const float* x      = (const float*)d_in[0];
    const float* w_in1  = (const float*)d_in[1];
    const float* b_in1  = (const float*)d_in[2];
    const float* w_out1 = (const float*)d_in[3];
    const float* b_out1 = (const float*)d_in[4];
    const float* w_in2  = (const float*)d_in[5];
    const float* b_in2  = (const float*)d_in[6];
    const float* w_out2 = (const float*)d_in[7];
    const float* b_out2 = (const float*)d_in[8];
    const float* g1     = (const float*)d_in[9];
    const float* be1    = (const float*)d_in[10];
    const float* g2     = (const float*)d_in[11];
    const float* be2    = (const float*)d_in[12];
    const float* g3     = (const float*)d_in[13];
    const float* be3    = (const float*)d_in[14];
    const float* w_ff1  = (const float*)d_in[15];
    const float* b_ff1  = (const float*)d_in[16];
    const float* w_ff2  = (const float*)d_in[17];
    const float* b_ff2  = (const float*)d_in[18];

    // workspace: bf16 elements; peak 50,331,648 elems = 100.66 MB (proven size)
    bf16* ws     = (bf16*)d_ws;
    bf16* xb     = ws + 0;            // [8,1024, 512]
    bf16* wq1    = ws + 4194304;      // [1536,512]   -- weights contiguous:
    bf16* wo1    = ws + 4980736;      // [512,512]
    bf16* wq2    = ws + 5242880;      // [1536,512]
    bf16* wo2    = ws + 6029312;      // [512,512]
    bf16* wf1    = ws + 6291456;      // [2048,512]
    bf16* wf2    = ws + 7340032;      // [512,2048]
    bf16* qkv1   = ws + 8388608;      // [8,1024,1536]
    bf16* o1     = ws + 20971520;     // [8,1024, 512]
    bf16* a1     = ws + 25165824;     // [8,1024, 512]
    bf16* x1     = ws + 29360128;     // [8,1024, 512]
    bf16* pooled = ws + 33554432;     // [8, 512, 512]
    bf16* qkv2   = ws + 35651584;     // [8, 512,1536]
    bf16* o2     = ws + 41943040;     // [8, 512, 512]
    bf16* a2     = ws + 44040192;     // [8, 512, 512]
    bf16* x2     = ws + 46137344;     // [8,1024, 512]
    bf16* h      = ws + 8388608;      // [8,1024,2048] (qkv1/o1 dead)
    bf16* ff     = ws + 25165824;     // [8,1024, 512] (a1 dead)
    bf16* vt     = ws + 46137344;     // [4096,1024] (x2 slot; dead before ln2 writes x2)

    dim3 blk(256);
    dim3 fblk(128);

    cvt_all<<<32768, blk, 0, stream>>>(x, w_in1, w_out1, w_in2, w_out2, w_ff1, w_ff2, xb);

    gemm_rs<0,128,1024><<<dim3(12, 64), blk, 0, stream>>>(xb, wq1, b_in1, qkv1, vt, 8192, 1536, 512);
    flash_attn_mfma<4><<<dim3(1024), fblk, 0, stream>>>(qkv1, vt, o1);
    gemm_rs<0,64,0><<<dim3(8, 64), blk, 0, stream>>>(o1, wo1, b_out1, a1, nullptr, 8192, 512, 512);
    ln_pool_kernel<<<4096, blk, 0, stream>>>(x, a1, g1, be1, x1, pooled);
    gemm_rs<0,64,512><<<dim3(24, 32), blk, 0, stream>>>(pooled, wq2, b_in2, qkv2, vt, 4096, 1536, 512);
    flash_attn_mfma<3><<<dim3(512), fblk, 0, stream>>>(qkv2, vt, o2);
    gemm_rs<0,64,0><<<dim3(8, 32), blk, 0, stream>>>(o2, wo2, b_out2, a2, nullptr, 4096, 512, 512);
    ln_kernel<bf16, bf16, true><<<8192, blk, 0, stream>>>(x1, a2, g2, be2, x2);
    gemm_rs<1,128,0><<<dim3(16, 64), blk, 0, stream>>>(x2, wf1, b_ff1, h, nullptr, 8192, 2048, 512);
    gemm_rs<0,64,0><<<dim3(8, 64), blk, 0, stream>>>(h, wf2, b_ff2, ff, nullptr, 8192, 512, 2048);
    ln_kernel<bf16, float, false><<<8192, blk, 0, stream>>>(x2, ff, g3, be3, (float*)d_out);
}

// Round 11
// 300.898 us; speedup vs baseline: 1.0501x; 1.0065x over previous
//
#include <hip/hip_runtime.h>
#include <hip/hip_bf16.h>
#include <math.h>

typedef __hip_bfloat16 bf16;
typedef __attribute__((ext_vector_type(8))) short short8;   // 8 bf16 = 4 VGPRs
typedef __attribute__((ext_vector_type(4))) float f32x4;    // 16x16 MFMA acc
typedef __attribute__((ext_vector_type(16))) float f32x16;  // 32x32 MFMA acc

__device__ __forceinline__ float ldf(const float* p, size_t i) { return p[i]; }
__device__ __forceinline__ float ldf(const bf16*  p, size_t i) { return __bfloat162float(p[i]); }
__device__ __forceinline__ void  stf(float* p, size_t i, float v) { p[i] = v; }
__device__ __forceinline__ void  stf(bf16*  p, size_t i, float v) { p[i] = __float2bfloat16(v); }

__device__ __forceinline__ float ex2(float x) { return __builtin_amdgcn_exp2f(x); }

// async global->LDS, 16 B per lane; dest = wave-uniform base + lane*16 (m97/m104)
__device__ __forceinline__ void gl16(const void* gp, void* lp) {
    __builtin_amdgcn_global_load_lds(
        (const __attribute__((address_space(1))) void*)gp,
        (__attribute__((address_space(3))) void*)lp, 16, 0, 0);
}

// v_permlane32_swap_b32: a' = {a.lo32lanes, b.lo32lanes}, b' = {a.hi, b.hi}
__device__ __forceinline__ void pl32swap(unsigned &a, unsigned &b) {
    asm volatile("v_permlane32_swap_b32 %0, %1" : "+v"(a), "+v"(b));
}

// ---------------------------------------------------------------------------
// fused fp32->bf16 convert: x (4,194,304 elems) then the 6 weight matrices
// (4,194,304 elems) into the contiguous ws region starting at xb.
// ---------------------------------------------------------------------------
__global__ __launch_bounds__(256) void cvt_all(
    const float* __restrict__ x,
    const float* __restrict__ s0, const float* __restrict__ s1,
    const float* __restrict__ s2, const float* __restrict__ s3,
    const float* __restrict__ s4, const float* __restrict__ s5,
    bf16* __restrict__ dst)
{
    int i = blockIdx.x * 256 + threadIdx.x;
    if (i < 4194304) {
        dst[i] = __float2bfloat16(x[i]);
        return;
    }
    int j = i - 4194304;
    const float* s; int off;
    if      (j <  786432) { s = s0; off = 0; }
    else if (j < 1048576) { s = s1; off =  786432; }
    else if (j < 1835008) { s = s2; off = 1048576; }
    else if (j < 2097152) { s = s3; off = 1835008; }
    else if (j < 3145728) { s = s4; off = 2097152; }
    else                  { s = s5; off = 3145728; }
    dst[i] = __float2bfloat16(s[j - off]);
}

// ---------------------------------------------------------------------------
// MFMA GEMM, SINGLE-buffered LDS + T14 reg-staging (m97-style residency):
//  - 32 KB (BN=128) / 24 KB (BN=64) LDS -> 5-6 blocks/CU resident (vs 2 with
//    the old double buffer); per-iteration drain hides under OTHER blocks
//    (m114: cross-block MFMA/VALU overlap is the real pipeline on this chip)
//  - next tile's global loads issued to VGPRs BEFORE compute (T14); LDS
//    rewrite between two barriers after compute
//  - lds[row][gg] = glob[row][gg ^ (row&7)] swizzle (0 conflicts, verified)
//  - bijective XCD-chunked swizzle (all grids have nwg % 8 == 0)
// VS > 0 (= S): qkv mode - blocks with col0 >= 1024 hold the V-third; their
// epilogue writes TRANSPOSED to vt[(b*8+h)*64+d][S] and skips C.
// C[M,N] = act(A[M,K] @ W[N,K]^T + bias[N]); EPI: 0=none, 1=exact GELU.
// ---------------------------------------------------------------------------
template <int EPI, int BN, int VS>
__global__ __launch_bounds__(256) void gemm_rs(
    const bf16* __restrict__ A, const bf16* __restrict__ W,
    const float* __restrict__ bias, bf16* __restrict__ C,
    bf16* __restrict__ vt, int M, int N, int K)
{
    constexpr int WNC = BN / 2;     // wave col span
    constexpr int NT  = BN / 32;    // 16-col frags per wave
    constexpr int RB  = BN / 32;    // 32-row staging rounds for B

    __shared__ __align__(16) bf16 Asl[128 * 64];
    __shared__ __align__(16) bf16 Bsl[BN * 64];

    const int tid  = threadIdx.x;
    const int lane = tid & 63;
    const int wave = tid >> 6;
    const int wm   = wave >> 1, wn = wave & 1;
    const int l15  = lane & 15, quad = lane >> 4;

    // XCD-chunked swizzle (bijective: nwg % 8 == 0 for all launches)
    const int nwg = gridDim.x * gridDim.y;
    const int bid = blockIdx.y * gridDim.x + blockIdx.x;
    const int wid = (bid & 7) * (nwg >> 3) + (bid >> 3);
    const int bx  = wid % gridDim.x, by = wid / gridDim.x;
    const int row0 = by * 128, col0 = bx * BN;

    const int sr = tid >> 3;
    const int gg = tid & 7;

    const bf16* As[4]; const bf16* Ws[RB]; int loA[4], loB[RB];
    #pragma unroll
    for (int j = 0; j < 4; j++) {
        int row = j * 32 + sr;
        int gs  = (gg ^ (row & 7)) * 8;
        As[j]  = &A[(size_t)(row0 + row) * K + gs];
        loA[j] = row * 64 + gg * 8;
    }
    #pragma unroll
    for (int j = 0; j < RB; j++) {
        int row = j * 32 + sr;
        int gs  = (gg ^ (row & 7)) * 8;
        Ws[j]  = &W[(size_t)(col0 + row) * K + gs];
        loB[j] = row * 64 + gg * 8;
    }

    short8 ga[4], gb[RB];
    auto LOADG = [&](int k0) {
        #pragma unroll
        for (int j = 0; j < 4; j++) ga[j] = *(const short8*)(As[j] + k0);
        #pragma unroll
        for (int j = 0; j < RB; j++) gb[j] = *(const short8*)(Ws[j] + k0);
    };
    auto WRITEL = [&]() {
        #pragma unroll
        for (int j = 0; j < 4; j++) *(short8*)&Asl[loA[j]] = ga[j];
        #pragma unroll
        for (int j = 0; j < RB; j++) *(short8*)&Bsl[loB[j]] = gb[j];
    };

    f32x4 acc[4][NT] = {};
    const int nk = K >> 6;

    LOADG(0);
    WRITEL();
    __syncthreads();                       // first tile visible

    for (int i = 0; i < nk; i++) {
        if (i + 1 < nk) LOADG((i + 1) << 6);   // in flight over compute

        #pragma unroll
        for (int ks = 0; ks < 64; ks += 32) {
            short8 af[4], bfr[NT];
            const int g0 = (ks >> 3) + quad;
            const int col = (g0 ^ (l15 & 7)) * 8;   // un-swizzle on read
            #pragma unroll
            for (int mt = 0; mt < 4; mt++)
                af[mt] = *(const short8*)&Asl[(wm * 64 + mt * 16 + l15) * 64 + col];
            #pragma unroll
            for (int nt = 0; nt < NT; nt++)
                bfr[nt] = *(const short8*)&Bsl[(wn * WNC + nt * 16 + l15) * 64 + col];
            #pragma unroll
            for (int mt = 0; mt < 4; mt++)
                #pragma unroll
                for (int nt = 0; nt < NT; nt++)
                    acc[mt][nt] = __builtin_amdgcn_mfma_f32_16x16x32_bf16(
                        af[mt], bfr[nt], acc[mt][nt], 0, 0, 0);
        }

        if (i + 1 < nk) {
            __syncthreads();               // all waves done READING Asl/Bsl
            WRITEL();                      // loads already landed (vmcnt)
            __syncthreads();               // new tile visible
        }
    }

    if constexpr (VS > 0) {
        if (col0 >= 1024) {                // V-third: transposed store to vt
            constexpr int LS = (VS == 1024) ? 10 : 9;
            #pragma unroll
            for (int mt = 0; mt < 4; mt++) {
                int rowm = row0 + wm * 64 + mt * 16 + quad * 4;
                int b8 = rowm >> LS;
                int s4 = rowm & (VS - 1);
                #pragma unroll
                for (int nt = 0; nt < NT; nt++) {
                    int col = col0 + wn * WNC + nt * 16 + l15;
                    float bv = bias[col];
                    int hd = col - 1024;
                    union { bf16 b4[4]; unsigned long long u; } pk;
                    #pragma unroll
                    for (int r = 0; r < 4; r++)
                        pk.b4[r] = __float2bfloat16(acc[mt][nt][r] + bv);
                    *(unsigned long long*)&vt[
                        ((size_t)(b8 * 8 + (hd >> 6)) * 64 + (hd & 63)) * VS + s4] = pk.u;
                }
            }
            return;
        }
    }

    #pragma unroll
    for (int mt = 0; mt < 4; mt++) {
        int row = row0 + wm * 64 + mt * 16 + quad * 4;
        #pragma unroll
        for (int nt = 0; nt < NT; nt++) {
            int col = col0 + wn * WNC + nt * 16 + l15;
            float bv = bias[col];
            #pragma unroll
            for (int r = 0; r < 4; r++) {
                float v = acc[mt][nt][r] + bv;
                if (EPI == 1) v = 0.5f * v * (1.0f + erff(v * 0.70710678118654752f));
                C[(size_t)(row + r) * N + col] = __float2bfloat16(v);
            }
        }
    }
}

// ---------------------------------------------------------------------------
// MFMA flash attention v7 (round-10 verified):
//  - K and V both staged via gl16 with pre-swizzled source into linear
//    [2][64][64] LDS buffers; one barrier per k-tile
//  - fixed-bias softmax p = exp2(s*CE - 2); P in registers via cvt_pk +
//    permlane32_swap (T12); bijective XCD-chunked swizzle
// ---------------------------------------------------------------------------
template <int LQB>
__global__ __launch_bounds__(128) void flash_attn_mfma(
    const bf16* __restrict__ qkv, const bf16* __restrict__ vt,
    bf16* __restrict__ o)
{
    constexpr int S  = 64 << LQB;
    constexpr int nt = 1 << LQB;

    __shared__ __align__(16) bf16 Kl[2][64 * 64];
    __shared__ __align__(16) bf16 Vl[2][64 * 64];

    const int tid  = threadIdx.x;
    const int wave = tid >> 6, lane = tid & 63;
    const int l31  = lane & 31, hi = lane >> 5;

    const int r    = blockIdx.x;
    const int w    = (r & 7) * ((1 << LQB) * 8) + (r >> 3);
    const int qblk = w & ((1 << LQB) - 1);
    const int bh   = w >> LQB;
    const int h    = bh & 7, bb = bh >> 3;
    const int q0   = qblk * 64 + wave * 32;

    const bf16* base  = qkv + (size_t)bb * S * 1536 + h * 64;
    const bf16* vbase = vt + (size_t)bh * 64 * S;

    // Q fragments: lane(q=l31, hi) holds Q[q][c*16 + hi*8 + e]  (B-frag)
    short8 qf[4];
    #pragma unroll
    for (int c = 0; c < 4; c++)
        qf[c] = *(const short8*)&base[(size_t)(q0 + l31) * 1536 + c * 16 + hi * 8];

    const int sr = lane >> 3;
    const int sc = ((lane & 7) ^ sr) * 8;   // swizzled source granule

    auto STGKV = [&](int buf, int k0) {
        #pragma unroll
        for (int t = 0; t < 4; t++) {
            int r0 = wave * 32 + t * 8;     // k-rows, wave-uniform
            gl16(&base[(size_t)(k0 + r0 + sr) * 1536 + 512 + sc], &Kl[buf][r0 * 64]);
        }
        #pragma unroll
        for (int t = 0; t < 4; t++) {
            int r0 = wave * 32 + t * 8;     // d-rows of V^T, wave-uniform
            gl16(&vbase[(size_t)(r0 + sr) * S + k0 + sc], &Vl[buf][r0 * 64]);
        }
    };

    f32x16 oacc[2] = {};
    float lrow = 0.f;
    const float CE = 0.18033688f;   // 0.125 * log2(e)

    STGKV(0, 0);

    for (int it = 0; it < nt; it++) {
        const int cur = it & 1;
        __syncthreads();                         // Kl/Vl[cur] staged & visible
        if (it + 1 < nt) STGKV(cur ^ 1, (it + 1) << 6);   // in flight over compute

        const bf16* Kc = &Kl[cur][0];
        const bf16* Vc = &Vl[cur][0];
        #pragma unroll
        for (int sub = 0; sub < 2; sub++) {
            // S^T = K @ Q^T (32k x 32q); lane(l31=q): k=(r2&3)+8*(r2>>2)+4*hi
            f32x16 st = {};
            #pragma unroll
            for (int c = 0; c < 4; c++) {
                const int row  = sub * 32 + l31;
                const int slot = (c * 2 + hi) ^ (row & 7);
                short8 af = *(const short8*)&Kc[row * 64 + slot * 8];
                st = __builtin_amdgcn_mfma_f32_32x32x16_bf16(af, qf[c], st, 0, 0, 0);
            }

            // fixed-bias exp2; per-lane partial row sum (combined at end)
            float p[16]; float ps = 0.f;
            #pragma unroll
            for (int r2 = 0; r2 < 16; r2++) {
                p[r2] = ex2(st[r2] * CE - 2.0f);
                ps += p[r2];
            }
            lrow += ps;

            unsigned wk[8];
            #pragma unroll
            for (int jj = 0; jj < 8; jj++)
                asm("v_cvt_pk_bf16_f32 %0, %1, %2"
                    : "=v"(wk[jj]) : "v"(p[2*jj]), "v"(p[2*jj+1]));

            #pragma unroll
            for (int kk = 0; kk < 2; kk++) {
                pl32swap(wk[kk*4+0], wk[kk*4+2]);
                pl32swap(wk[kk*4+1], wk[kk*4+3]);
                union { unsigned u[4]; short8 s; } pa;
                pa.u[0] = wk[kk*4+0]; pa.u[1] = wk[kk*4+1];
                pa.u[2] = wk[kk*4+2]; pa.u[3] = wk[kk*4+3];
                #pragma unroll
                for (int dt = 0; dt < 2; dt++) {
                    const int row  = dt * 32 + l31;               // d-row
                    const int slot = (sub * 4 + kk * 2 + hi) ^ (row & 7);
                    short8 vf = *(const short8*)&Vc[row * 64 + slot * 8];
                    oacc[dt] = __builtin_amdgcn_mfma_f32_32x32x16_bf16(
                        pa.s, vf, oacc[dt], 0, 0, 0);
                }
            }
        }
    }

    // combine the two k-halves of each q-row, normalize, store
    lrow += __shfl_xor(lrow, 32);
    float inv = 1.0f / lrow;
    #pragma unroll
    for (int r2 = 0; r2 < 16; r2++) {
        int qr = (r2 & 3) + 8 * (r2 >> 2) + 4 * hi;
        float iv = __shfl(inv, qr);
        size_t rb = ((size_t)bb * S + q0 + qr) * 512 + h * 64;
        o[rb + l31]      = __float2bfloat16(oacc[0][r2] * iv);
        o[rb + 32 + l31] = __float2bfloat16(oacc[1][r2] * iv);
    }
}

// ---------------------------------------------------------------------------
// out = LN(a + b) * g + beta over D=512. One block (256 thr) per row.
// ---------------------------------------------------------------------------
template <typename AT, typename OT, bool INTERP>
__global__ __launch_bounds__(256) void ln_kernel(
    const AT* __restrict__ a, const bf16* __restrict__ bsrc,
    const float* __restrict__ g, const float* __restrict__ beta,
    OT* __restrict__ out)
{
    const int row = blockIdx.x;
    const int t = threadIdx.x;
    const size_t base = (size_t)row * 512;

    float a0 = ldf(a, base + t), a1 = ldf(a, base + t + 256);
    float b0, b1;
    if (INTERP) {
        int s = row & 1023, bb = row >> 10;
        float src = fminf(fmaxf((s + 0.5f) * 0.5f - 0.5f, 0.f), 511.f);
        int i0 = (int)src;
        int i1 = min(i0 + 1, 511);
        float w = src - (float)i0;
        size_t r0 = ((size_t)bb * 512 + i0) * 512;
        size_t r1 = ((size_t)bb * 512 + i1) * 512;
        b0 = __bfloat162float(bsrc[r0 + t]) * (1.f - w) + __bfloat162float(bsrc[r1 + t]) * w;
        b1 = __bfloat162float(bsrc[r0 + t + 256]) * (1.f - w) + __bfloat162float(bsrc[r1 + t + 256]) * w;
    } else {
        b0 = __bfloat162float(bsrc[base + t]);
        b1 = __bfloat162float(bsrc[base + t + 256]);
    }
    float v0 = a0 + b0, v1 = a1 + b1;

    __shared__ float red[4];
    const int lane = t & 63, wid = t >> 6;

    float sm = v0 + v1;
    #pragma unroll
    for (int off = 32; off > 0; off >>= 1) sm += __shfl_xor(sm, off);
    if (lane == 0) red[wid] = sm;
    __syncthreads();
    sm = red[0] + red[1] + red[2] + red[3];
    const float mean = sm * (1.0f / 512.0f);

    float d0 = v0 - mean, d1 = v1 - mean;
    float vv = d0 * d0 + d1 * d1;
    __syncthreads();
    #pragma unroll
    for (int off = 32; off > 0; off >>= 1) vv += __shfl_xor(vv, off);
    if (lane == 0) red[wid] = vv;
    __syncthreads();
    vv = red[0] + red[1] + red[2] + red[3];
    const float rstd = rsqrtf(vv * (1.0f / 512.0f) + 1e-5f);

    stf(out, base + t,       d0 * rstd * g[t]       + beta[t]);
    stf(out, base + t + 256, d1 * rstd * g[t + 256] + beta[t + 256]);
}

// ---------------------------------------------------------------------------
// Fused ln1 + avg_pool: one block per ROW-PAIR (2s, 2s+1). Computes both
// LN rows of x1 and the pooled row = 0.5*(x1[2s]+x1[2s+1]).
// ---------------------------------------------------------------------------
__global__ __launch_bounds__(256) void ln_pool_kernel(
    const float* __restrict__ a, const bf16* __restrict__ bsrc,
    const float* __restrict__ g, const float* __restrict__ beta,
    bf16* __restrict__ x1, bf16* __restrict__ pooled)
{
    const int pr = blockIdx.x;              // pooled row 0..4095
    const int t = threadIdx.x;
    const size_t base0 = (size_t)(2 * pr) * 512;
    const size_t base1 = base0 + 512;

    float u0 = a[base0 + t]       + __bfloat162float(bsrc[base0 + t]);
    float u1 = a[base0 + t + 256] + __bfloat162float(bsrc[base0 + t + 256]);
    float w0 = a[base1 + t]       + __bfloat162float(bsrc[base1 + t]);
    float w1 = a[base1 + t + 256] + __bfloat162float(bsrc[base1 + t + 256]);

    __shared__ float red[2][4];
    const int lane = t & 63, wid = t >> 6;

    float s0 = u0 + u1, s1 = w0 + w1;
    #pragma unroll
    for (int off = 32; off > 0; off >>= 1) {
        s0 += __shfl_xor(s0, off);
        s1 += __shfl_xor(s1, off);
    }
    if (lane == 0) { red[0][wid] = s0; red[1][wid] = s1; }
    __syncthreads();
    const float m0 = (red[0][0] + red[0][1] + red[0][2] + red[0][3]) * (1.0f / 512.0f);
    const float m1 = (red[1][0] + red[1][1] + red[1][2] + red[1][3]) * (1.0f / 512.0f);

    float du0 = u0 - m0, du1 = u1 - m0, dw0 = w0 - m1, dw1 = w1 - m1;
    float v0 = du0 * du0 + du1 * du1, v1 = dw0 * dw0 + dw1 * dw1;
    __syncthreads();
    #pragma unroll
    for (int off = 32; off > 0; off >>= 1) {
        v0 += __shfl_xor(v0, off);
        v1 += __shfl_xor(v1, off);
    }
    if (lane == 0) { red[0][wid] = v0; red[1][wid] = v1; }
    __syncthreads();
    const float r0 = rsqrtf((red[0][0] + red[0][1] + red[0][2] + red[0][3]) * (1.0f / 512.0f) + 1e-5f);
    const float r1 = rsqrtf((red[1][0] + red[1][1] + red[1][2] + red[1][3]) * (1.0f / 512.0f) + 1e-5f);

    float g0 = g[t], g1v = g[t + 256], be0 = beta[t], be1 = beta[t + 256];
    float y00 = du0 * r0 * g0  + be0;
    float y01 = du1 * r0 * g1v + be1;
    float y10 = dw0 * r1 * g0  + be0;
    float y11 = dw1 * r1 * g1v + be1;

    x1[base0 + t]       = __float2bfloat16(y00);
    x1[base0 + t + 256] = __float2bfloat16(y01);
    x1[base1 + t]       = __float2bfloat16(y10);
    x1[base1 + t + 256] = __float2bfloat16(y11);

    const size_t pb = (size_t)pr * 512;
    pooled[pb + t]       = __float2bfloat16(0.5f * (y00 + y10));
    pooled[pb + t + 256] = __float2bfloat16(0.5f * (y01 + y11));
}

// ---------------------------------------------------------------------------
// launch
// ---------------------------------------------------------------------------
extern "C" void kernel_launch(void* const* d_in, const int* in_sizes, int n_in,
                              void* d_out, int out_size, void* d_ws, size_t ws_size,
                              hipStream_t stream)
{
    const float* x      = (const float*)d_in[0];
    const float* w_in1  = (const float*)d_in[1];
    const float* b_in1  = (const float*)d_in[2];
    const float* w_out1 = (const float*)d_in[3];
    const float* b_out1 = (const float*)d_in[4];
    const float* w_in2  = (const float*)d_in[5];
    const float* b_in2  = (const float*)d_in[6];
    const float* w_out2 = (const float*)d_in[7];
    const float* b_out2 = (const float*)d_in[8];
    const float* g1     = (const float*)d_in[9];
    const float* be1    = (const float*)d_in[10];
    const float* g2     = (const float*)d_in[11];
    const float* be2    = (const float*)d_in[12];
    const float* g3     = (const float*)d_in[13];
    const float* be3    = (const float*)d_in[14];
    const float* w_ff1  = (const float*)d_in[15];
    const float* b_ff1  = (const float*)d_in[16];
    const float* w_ff2  = (const float*)d_in[17];
    const float* b_ff2  = (const float*)d_in[18];

    // workspace: bf16 elements; peak 50,331,648 elems = 100.66 MB (proven size)
    bf16* ws     = (bf16*)d_ws;
    bf16* xb     = ws + 0;            // [8,1024, 512]
    bf16* wq1    = ws + 4194304;      // [1536,512]   -- weights contiguous:
    bf16* wo1    = ws + 4980736;      // [512,512]
    bf16* wq2    = ws + 5242880;      // [1536,512]
    bf16* wo2    = ws + 6029312;      // [512,512]
    bf16* wf1    = ws + 6291456;      // [2048,512]
    bf16* wf2    = ws + 7340032;      // [512,2048]
    bf16* qkv1   = ws + 8388608;      // [8,1024,1536]
    bf16* o1     = ws + 20971520;     // [8,1024, 512]
    bf16* a1     = ws + 25165824;     // [8,1024, 512]
    bf16* x1     = ws + 29360128;     // [8,1024, 512]
    bf16* pooled = ws + 33554432;     // [8, 512, 512]
    bf16* qkv2   = ws + 35651584;     // [8, 512,1536]
    bf16* o2     = ws + 41943040;     // [8, 512, 512]
    bf16* a2     = ws + 44040192;     // [8, 512, 512]
    bf16* x2     = ws + 46137344;     // [8,1024, 512]
    bf16* h      = ws + 8388608;      // [8,1024,2048] (qkv1/o1 dead)
    bf16* ff     = ws + 25165824;     // [8,1024, 512] (a1 dead)
    bf16* vt     = ws + 46137344;     // [4096,1024] (x2 slot; dead before ln2 writes x2)

    dim3 blk(256);
    dim3 fblk(128);

    cvt_all<<<32768, blk, 0, stream>>>(x, w_in1, w_out1, w_in2, w_out2, w_ff1, w_ff2, xb);

    gemm_rs<0,128,1024><<<dim3(12, 64), blk, 0, stream>>>(xb, wq1, b_in1, qkv1, vt, 8192, 1536, 512);
    flash_attn_mfma<4><<<dim3(1024), fblk, 0, stream>>>(qkv1, vt, o1);
    gemm_rs<0,64,0><<<dim3(8, 64), blk, 0, stream>>>(o1, wo1, b_out1, a1, nullptr, 8192, 512, 512);
    ln_pool_kernel<<<4096, blk, 0, stream>>>(x, a1, g1, be1, x1, pooled);
    gemm_rs<0,64,512><<<dim3(24, 32), blk, 0, stream>>>(pooled, wq2, b_in2, qkv2, vt, 4096, 1536, 512);
    flash_attn_mfma<3><<<dim3(512), fblk, 0, stream>>>(qkv2, vt, o2);
    gemm_rs<0,64,0><<<dim3(8, 32), blk, 0, stream>>>(o2, wo2, b_out2, a2, nullptr, 4096, 512, 512);
    ln_kernel<bf16, bf16, true><<<8192, blk, 0, stream>>>(x1, a2, g2, be2, x2);
    gemm_rs<1,128,0><<<dim3(16, 64), blk, 0, stream>>>(x2, wf1, b_ff1, h, nullptr, 8192, 2048, 512);
    gemm_rs<0,64,0><<<dim3(8, 64), blk, 0, stream>>>(h, wf2, b_ff2, ff, nullptr, 8192, 512, 2048);
    ln_kernel<bf16, float, false><<<8192, blk, 0, stream>>>(x2, ff, g3, be3, (float*)d_out);
}